// Round 10
// baseline (92.122 us; speedup 1.0000x reference)
//
#include <hip/hip_runtime.h>
#include <hip/hip_cooperative_groups.h>
#include <math.h>

#define NF 50
#define REC 52           // per-block record: 50 z + s + pad
#define NBLK 512         // 2 blocks/CU at (512,4) -> exactly co-resident
#define LOG2E 1.44269504f

// DPP ctrl codes
#define DPP_QXOR1 0xB1   // quad_perm [1,0,3,2]
#define DPP_QXOR2 0x4E   // quad_perm [2,3,0,1]
#define DPP_ROR4  0x124  // row_ror:4
#define DPP_ROR8  0x128  // row_ror:8

__device__ __forceinline__ float dpp_add(float v, int ctrl) {
    float t;
    switch (ctrl) {  // ctrl must be an ICE for the builtin
      case DPP_QXOR1: t = __int_as_float(__builtin_amdgcn_update_dpp(0, __float_as_int(v), DPP_QXOR1, 0xF, 0xF, true)); break;
      case DPP_QXOR2: t = __int_as_float(__builtin_amdgcn_update_dpp(0, __float_as_int(v), DPP_QXOR2, 0xF, 0xF, true)); break;
      case DPP_ROR4:  t = __int_as_float(__builtin_amdgcn_update_dpp(0, __float_as_int(v), DPP_ROR4,  0xF, 0xF, true)); break;
      default:        t = __int_as_float(__builtin_amdgcn_update_dpp(0, __float_as_int(v), DPP_ROR8,  0xF, 0xF, true)); break;
    }
    return v + t;
}

// Fused cooperative kernel. Main loop = R8's proven quad-per-row pass1
// (one hardware quad per row; lane q owns float2 slots q+4t). After the
// block record is written, grid.sync(); block 0 merges the 512 records
// (106 KB, L2-hot) and writes out. No conditional liveness added to the
// hot loop -> register allocation identical to R8's pass1 (~75 VGPR).
__global__ __launch_bounds__(512, 4) void attn_fused(
    const float* __restrict__ query, const float* __restrict__ ql_w,
    const float* __restrict__ qWp, float* __restrict__ ws,
    float* __restrict__ out, int T, int totalGroups, int nBlocks)
{
    const float qW = qWp[0];
    const int tid = threadIdx.x;
    const int q   = tid & 3;                       // lane within quad
    const int g   = blockIdx.x * 128 + (tid >> 2); // global group id (row stream)

    // per-lane weights for slots q+4t
    float2 w01[7];
    #pragma unroll
    for (int t = 0; t < 6; ++t) {
        const int s = q + 4 * t;
        w01[t] = *(const float2*)(ql_w + 2 * s);
    }
    w01[6] = (q == 0) ? *(const float2*)(ql_w + 48) : make_float2(0.f, 0.f);
    const int d6 = (q == 0) ? 192 : 160;           // 7th-slot byte offset from rp

    // sumW / sumAbsW: per-lane partial over its slots, then quad reduce.
    float sw = 0.f, saw = 0.f;
    #pragma unroll
    for (int t = 0; t < 7; ++t) {
        sw  += w01[t].x + w01[t].y;
        saw += fabsf(w01[t].x) + fabsf(w01[t].y);
    }
    sw  = dpp_add(dpp_add(sw,  DPP_QXOR1), DPP_QXOR2);
    saw = dpp_add(dpp_add(saw, DPP_QXOR1), DPP_QXOR2);
    const float M0  = (saw > 80.f) ? (saw - 80.f) : 0.f;   // overflow guard; 0 here
    const float c2  = 2.f * qW * LOG2E;
    const float K   = (sw - M0) * LOG2E;
    const float n2l = -2.f * LOG2E;

    float2 z[7];
    #pragma unroll
    for (int t = 0; t < 7; ++t) z[t] = make_float2(0.f, 0.f);
    float se = 0.f;

    const int G = totalGroups;                     // NBLK*128 = 65536
    const char* rp = (const char*)(query + (size_t)g * NF) + (q << 3);
    const size_t step = (size_t)G * NF * sizeof(float);

    for (int row = g; row < T; row += G, rp += step) {
        float2 x0 = *(const float2*)(rp);
        float2 x1 = *(const float2*)(rp + 32);
        float2 x2 = *(const float2*)(rp + 64);
        float2 x3 = *(const float2*)(rp + 96);
        float2 x4 = *(const float2*)(rp + 128);
        float2 x5 = *(const float2*)(rp + 160);
        float2 x6 = *(const float2*)(rp + d6);

        float p = 0.f;
        {
            float r;
            r = __builtin_amdgcn_rcpf(__builtin_amdgcn_exp2f(c2 * x0.x) + 1.f); p = fmaf(w01[0].x, r, p);
            r = __builtin_amdgcn_rcpf(__builtin_amdgcn_exp2f(c2 * x0.y) + 1.f); p = fmaf(w01[0].y, r, p);
            r = __builtin_amdgcn_rcpf(__builtin_amdgcn_exp2f(c2 * x1.x) + 1.f); p = fmaf(w01[1].x, r, p);
            r = __builtin_amdgcn_rcpf(__builtin_amdgcn_exp2f(c2 * x1.y) + 1.f); p = fmaf(w01[1].y, r, p);
            r = __builtin_amdgcn_rcpf(__builtin_amdgcn_exp2f(c2 * x2.x) + 1.f); p = fmaf(w01[2].x, r, p);
            r = __builtin_amdgcn_rcpf(__builtin_amdgcn_exp2f(c2 * x2.y) + 1.f); p = fmaf(w01[2].y, r, p);
            r = __builtin_amdgcn_rcpf(__builtin_amdgcn_exp2f(c2 * x3.x) + 1.f); p = fmaf(w01[3].x, r, p);
            r = __builtin_amdgcn_rcpf(__builtin_amdgcn_exp2f(c2 * x3.y) + 1.f); p = fmaf(w01[3].y, r, p);
            r = __builtin_amdgcn_rcpf(__builtin_amdgcn_exp2f(c2 * x4.x) + 1.f); p = fmaf(w01[4].x, r, p);
            r = __builtin_amdgcn_rcpf(__builtin_amdgcn_exp2f(c2 * x4.y) + 1.f); p = fmaf(w01[4].y, r, p);
            r = __builtin_amdgcn_rcpf(__builtin_amdgcn_exp2f(c2 * x5.x) + 1.f); p = fmaf(w01[5].x, r, p);
            r = __builtin_amdgcn_rcpf(__builtin_amdgcn_exp2f(c2 * x5.y) + 1.f); p = fmaf(w01[5].y, r, p);
            r = __builtin_amdgcn_rcpf(__builtin_amdgcn_exp2f(c2 * x6.x) + 1.f); p = fmaf(w01[6].x, r, p);
            r = __builtin_amdgcn_rcpf(__builtin_amdgcn_exp2f(c2 * x6.y) + 1.f); p = fmaf(w01[6].y, r, p);
        }
        p = dpp_add(dpp_add(p, DPP_QXOR1), DPP_QXOR2);  // full 50-feature sum
        const float e = __builtin_amdgcn_exp2f(fmaf(p, n2l, K));

        se += e;
        z[0].x = fmaf(e, x0.x, z[0].x); z[0].y = fmaf(e, x0.y, z[0].y);
        z[1].x = fmaf(e, x1.x, z[1].x); z[1].y = fmaf(e, x1.y, z[1].y);
        z[2].x = fmaf(e, x2.x, z[2].x); z[2].y = fmaf(e, x2.y, z[2].y);
        z[3].x = fmaf(e, x3.x, z[3].x); z[3].y = fmaf(e, x3.y, z[3].y);
        z[4].x = fmaf(e, x4.x, z[4].x); z[4].y = fmaf(e, x4.y, z[4].y);
        z[5].x = fmaf(e, x5.x, z[5].x); z[5].y = fmaf(e, x5.y, z[5].y);
        z[6].x = fmaf(e, x6.x, z[6].x); z[6].y = fmaf(e, x6.y, z[6].y);
    }

    // Sum the 4 quads within each 16-lane row.
    #pragma unroll
    for (int t = 0; t < 7; ++t) {
        z[t].x = dpp_add(dpp_add(z[t].x, DPP_ROR4), DPP_ROR8);
        z[t].y = dpp_add(dpp_add(z[t].y, DPP_ROR4), DPP_ROR8);
    }
    se = dpp_add(dpp_add(se, DPP_ROR4), DPP_ROR8);

    __shared__ float sz[32][REC];
    if ((tid & 15) < 4) {                  // one writer per q per 16-row
        const int eidx = tid >> 4;         // 0..31
        #pragma unroll
        for (int t = 0; t < 6; ++t) {
            const int s = q + 4 * t;
            *(float2*)&sz[eidx][2 * s] = z[t];
        }
        if (q == 0) {
            *(float2*)&sz[eidx][48] = z[6];
            sz[eidx][50] = se;
            sz[eidx][51] = 0.f;
        }
    }
    __syncthreads();

    if (tid < 51) {
        float acc = 0.f;
        #pragma unroll
        for (int h = 0; h < 32; ++h) acc += sz[h][tid];
        ws[(size_t)blockIdx.x * REC + tid] = acc;
    }

    // ---- fuse pass2: grid-wide sync, then block 0 merges 512 records ----
    cooperative_groups::this_grid().sync();

    if (blockIdx.x == 0) {
        const int w = tid >> 6, lane = tid & 63;   // 8 waves
        if (lane < 51) {
            float acc = 0.f;
            int b = w;
            for (; b + 24 < nBlocks; b += 32) {
                acc += ws[(size_t)(b     ) * REC + lane]
                     + ws[(size_t)(b +  8) * REC + lane]
                     + ws[(size_t)(b + 16) * REC + lane]
                     + ws[(size_t)(b + 24) * REC + lane];
            }
            for (; b < nBlocks; b += 8)
                acc += ws[(size_t)b * REC + lane];
            sz[w][lane] = acc;                     // reuse LDS (post-sync safe)
        }
        __syncthreads();
        if (tid < NF) {
            float Z = 0.f, S = 0.f;
            #pragma unroll
            for (int h = 0; h < 8; ++h) { Z += sz[h][tid]; S += sz[h][50]; }
            out[tid] = Z / S;
        }
    }
}

extern "C" void kernel_launch(void* const* d_in, const int* in_sizes, int n_in,
                              void* d_out, int out_size, void* d_ws, size_t ws_size,
                              hipStream_t stream) {
    const float* query = (const float*)d_in[0];
    const float* ql_w  = (const float*)d_in[1];
    const float* qW    = (const float*)d_in[2];
    float* out = (float*)d_out;
    float* ws  = (float*)d_ws;

    int T = in_sizes[0] / NF;

    int B = NBLK;
    size_t need = (size_t)B * REC * sizeof(float);
    if (ws_size < need) {
        B = (int)(ws_size / (REC * sizeof(float)));
        if (B < 1) B = 1;
    }

    int totalGroups = B * 128;
    void* args[] = { (void*)&query, (void*)&ql_w, (void*)&qW, (void*)&ws,
                     (void*)&out, (void*)&T, (void*)&totalGroups, (void*)&B };
    hipLaunchCooperativeKernel((void*)attn_fused, dim3(B), dim3(512),
                               args, 0, stream);
}

// Round 11
// 26.514 us; speedup vs baseline: 3.4745x; 3.4745x over previous
//
#include <hip/hip_runtime.h>
#include <math.h>

#define NF 50
#define REC 52           // per-block record: 50 z + s + pad
#define NBLK 512         // 2 blocks/CU at (512,4) -> exactly co-resident
#define LOG2E 1.44269504f

// DPP ctrl codes
#define DPP_QXOR1 0xB1   // quad_perm [1,0,3,2]
#define DPP_QXOR2 0x4E   // quad_perm [2,3,0,1]
#define DPP_ROR4  0x124  // row_ror:4
#define DPP_ROR8  0x128  // row_ror:8

__device__ __forceinline__ float dpp_add(float v, int ctrl) {
    float t;
    switch (ctrl) {  // ctrl must be an ICE for the builtin
      case DPP_QXOR1: t = __int_as_float(__builtin_amdgcn_update_dpp(0, __float_as_int(v), DPP_QXOR1, 0xF, 0xF, true)); break;
      case DPP_QXOR2: t = __int_as_float(__builtin_amdgcn_update_dpp(0, __float_as_int(v), DPP_QXOR2, 0xF, 0xF, true)); break;
      case DPP_ROR4:  t = __int_as_float(__builtin_amdgcn_update_dpp(0, __float_as_int(v), DPP_ROR4,  0xF, 0xF, true)); break;
      default:        t = __int_as_float(__builtin_amdgcn_update_dpp(0, __float_as_int(v), DPP_ROR8,  0xF, 0xF, true)); break;
    }
    return v + t;
}

// t = 1/(e^{2qWx}+1) building block (tanh = 1-2t); exp2-based.
#define RCPE(v) __builtin_amdgcn_rcpf(__builtin_amdgcn_exp2f(c2 * (v)) + 1.f)

// Pass 1 (even T): one quad per ROW PAIR (400 B, 16B-aligned, 25 float4).
// Lane q owns float4 chunks q+4t (t=0..5; byte offset q*16 + 64t) plus
// scalar float 96+q. 3.5 VMEM instr/row (vs 7), zero dummy elements.
// Chunk 12 (floats 48..51) straddles rows: weights statically split
// (w3r0/w3r1); z-scale blended via ez = fmaf(m3, e0-e1, e1).
// Epilogue: slot = global float index (bijective, 100 slots + s).
__global__ __launch_bounds__(512, 4) void attn_pass1_even(
    const float* __restrict__ query, const float* __restrict__ ql_w,
    const float* __restrict__ qWp, float* __restrict__ ws,
    int T, int totalGroups)
{
    const float qW = qWp[0];
    const int tid = threadIdx.x;
    const int q   = tid & 3;                       // lane within quad
    const int g   = blockIdx.x * 128 + (tid >> 2); // pair-stream id

    // weights for chunks q+4t; feature = (4c+i) mod 50
    float4 w4[6];
    #pragma unroll
    for (int t = 0; t < 6; ++t) {
        const int c = q + 4 * t;
        const int f0 = 4*c, f1 = 4*c+1, f2 = 4*c+2, f3 = 4*c+3;
        w4[t] = make_float4(ql_w[f0 >= 50 ? f0-50 : f0],
                            ql_w[f1 >= 50 ? f1-50 : f1],
                            ql_w[f2 >= 50 ? f2-50 : f2],
                            ql_w[f3 >= 50 ? f3-50 : f3]);
    }
    const float wsc = ql_w[46 + q];                // scalar slot 96+q -> row1 feat 46+q

    // sumW / sumAbsW: per-lane covers each feature exactly twice -> *0.5
    float sw = wsc, saw = fabsf(wsc);
    #pragma unroll
    for (int t = 0; t < 6; ++t) {
        sw  += (w4[t].x + w4[t].y) + (w4[t].z + w4[t].w);
        saw += (fabsf(w4[t].x) + fabsf(w4[t].y)) + (fabsf(w4[t].z) + fabsf(w4[t].w));
    }
    sw  = dpp_add(dpp_add(sw,  DPP_QXOR1), DPP_QXOR2) * 0.5f;
    saw = dpp_add(dpp_add(saw, DPP_QXOR1), DPP_QXOR2) * 0.5f;
    const float M0  = (saw > 80.f) ? (saw - 80.f) : 0.f;   // overflow guard; 0 here
    const float c2  = 2.f * qW * LOG2E;
    const float K   = (sw - M0) * LOG2E;
    const float n2l = -2.f * LOG2E;

    // chunk-3 (c=12+q) row split: lane0 elems x,y are row0 (floats 48,49);
    // everything else in chunk 3 is row1.
    float4 w3r0, w3r1;
    if (q == 0) { w3r0 = make_float4(w4[3].x, w4[3].y, 0.f, 0.f);
                  w3r1 = make_float4(0.f, 0.f, w4[3].z, w4[3].w); }
    else        { w3r0 = make_float4(0.f, 0.f, 0.f, 0.f);
                  w3r1 = w4[3]; }
    const float m3 = (q == 0) ? 1.f : 0.f;

    float4 z0 = {0,0,0,0}, z1 = {0,0,0,0}, z2 = {0,0,0,0},
           z3 = {0,0,0,0}, z4 = {0,0,0,0}, z5 = {0,0,0,0};
    float zsc = 0.f, se = 0.f;

    const int TP = T >> 1;
    const int G  = totalGroups;                    // NBLK*128 = 65536
    const char* rp = (const char*)query + (size_t)g * 400 + (q << 4);
    const int off_s = 384 - 12 * q;                // scalar float byte offset from rp
    const size_t step = (size_t)G * 400;

    for (int pr = g; pr < TP; pr += G, rp += step) {
        float4 x0 = *(const float4*)(rp);
        float4 x1 = *(const float4*)(rp + 64);
        float4 x2 = *(const float4*)(rp + 128);
        float4 x3 = *(const float4*)(rp + 192);
        float4 x4 = *(const float4*)(rp + 256);
        float4 x5 = *(const float4*)(rp + 320);
        float  xs = *(const float*)(rp + off_s);

        float p0 = 0.f, p1 = 0.f, r;
        r = RCPE(x0.x); p0 = fmaf(w4[0].x, r, p0);
        r = RCPE(x0.y); p0 = fmaf(w4[0].y, r, p0);
        r = RCPE(x0.z); p0 = fmaf(w4[0].z, r, p0);
        r = RCPE(x0.w); p0 = fmaf(w4[0].w, r, p0);
        r = RCPE(x1.x); p0 = fmaf(w4[1].x, r, p0);
        r = RCPE(x1.y); p0 = fmaf(w4[1].y, r, p0);
        r = RCPE(x1.z); p0 = fmaf(w4[1].z, r, p0);
        r = RCPE(x1.w); p0 = fmaf(w4[1].w, r, p0);
        r = RCPE(x2.x); p0 = fmaf(w4[2].x, r, p0);
        r = RCPE(x2.y); p0 = fmaf(w4[2].y, r, p0);
        r = RCPE(x2.z); p0 = fmaf(w4[2].z, r, p0);
        r = RCPE(x2.w); p0 = fmaf(w4[2].w, r, p0);
        {   // straddling chunk
            float r3x = RCPE(x3.x), r3y = RCPE(x3.y);
            float r3z = RCPE(x3.z), r3w = RCPE(x3.w);
            p0 = fmaf(w3r0.x, r3x, p0); p0 = fmaf(w3r0.y, r3y, p0);
            p1 = fmaf(w3r1.x, r3x, p1); p1 = fmaf(w3r1.y, r3y, p1);
            p1 = fmaf(w3r1.z, r3z, p1); p1 = fmaf(w3r1.w, r3w, p1);
        }
        r = RCPE(x4.x); p1 = fmaf(w4[4].x, r, p1);
        r = RCPE(x4.y); p1 = fmaf(w4[4].y, r, p1);
        r = RCPE(x4.z); p1 = fmaf(w4[4].z, r, p1);
        r = RCPE(x4.w); p1 = fmaf(w4[4].w, r, p1);
        r = RCPE(x5.x); p1 = fmaf(w4[5].x, r, p1);
        r = RCPE(x5.y); p1 = fmaf(w4[5].y, r, p1);
        r = RCPE(x5.z); p1 = fmaf(w4[5].z, r, p1);
        r = RCPE(x5.w); p1 = fmaf(w4[5].w, r, p1);
        r = RCPE(xs);   p1 = fmaf(wsc,     r, p1);

        p0 = dpp_add(dpp_add(p0, DPP_QXOR1), DPP_QXOR2);
        p1 = dpp_add(dpp_add(p1, DPP_QXOR1), DPP_QXOR2);
        const float e0 = __builtin_amdgcn_exp2f(fmaf(p0, n2l, K));
        const float e1 = __builtin_amdgcn_exp2f(fmaf(p1, n2l, K));
        se += e0 + e1;
        const float ez3 = fmaf(m3, e0 - e1, e1);   // e0 on lane0 (row0 elems), else e1

        z0.x = fmaf(e0, x0.x, z0.x); z0.y = fmaf(e0, x0.y, z0.y);
        z0.z = fmaf(e0, x0.z, z0.z); z0.w = fmaf(e0, x0.w, z0.w);
        z1.x = fmaf(e0, x1.x, z1.x); z1.y = fmaf(e0, x1.y, z1.y);
        z1.z = fmaf(e0, x1.z, z1.z); z1.w = fmaf(e0, x1.w, z1.w);
        z2.x = fmaf(e0, x2.x, z2.x); z2.y = fmaf(e0, x2.y, z2.y);
        z2.z = fmaf(e0, x2.z, z2.z); z2.w = fmaf(e0, x2.w, z2.w);
        z3.x = fmaf(ez3, x3.x, z3.x); z3.y = fmaf(ez3, x3.y, z3.y);
        z3.z = fmaf(e1,  x3.z, z3.z); z3.w = fmaf(e1,  x3.w, z3.w);
        z4.x = fmaf(e1, x4.x, z4.x); z4.y = fmaf(e1, x4.y, z4.y);
        z4.z = fmaf(e1, x4.z, z4.z); z4.w = fmaf(e1, x4.w, z4.w);
        z5.x = fmaf(e1, x5.x, z5.x); z5.y = fmaf(e1, x5.y, z5.y);
        z5.z = fmaf(e1, x5.z, z5.z); z5.w = fmaf(e1, x5.w, z5.w);
        zsc  = fmaf(e1, xs, zsc);
    }

    // sum the 4 quads within each 16-lane row (same q -> same slots)
    #define RED(v) v = dpp_add(dpp_add(v, DPP_ROR4), DPP_ROR8)
    RED(z0.x); RED(z0.y); RED(z0.z); RED(z0.w);
    RED(z1.x); RED(z1.y); RED(z1.z); RED(z1.w);
    RED(z2.x); RED(z2.y); RED(z2.z); RED(z2.w);
    RED(z3.x); RED(z3.y); RED(z3.z); RED(z3.w);
    RED(z4.x); RED(z4.y); RED(z4.z); RED(z4.w);
    RED(z5.x); RED(z5.y); RED(z5.z); RED(z5.w);
    RED(zsc);  RED(se);
    #undef RED

    __shared__ float s100[32][104];   // 100 slots + s at [100]; 104 keeps 16B rows
    const int eidx = tid >> 4;
    if ((tid & 15) < 4) {
        *(float4*)&s100[eidx][4 * (q     )] = z0;
        *(float4*)&s100[eidx][4 * (q +  4)] = z1;
        *(float4*)&s100[eidx][4 * (q +  8)] = z2;
        *(float4*)&s100[eidx][4 * (q + 12)] = z3;
        *(float4*)&s100[eidx][4 * (q + 16)] = z4;
        *(float4*)&s100[eidx][4 * (q + 20)] = z5;
        s100[eidx][96 + q] = zsc;
        if (q == 0) s100[eidx][100] = se;
    }
    __syncthreads();

    if (tid < 50) {
        float acc = 0.f;
        #pragma unroll
        for (int h = 0; h < 32; ++h) acc += s100[h][tid] + s100[h][tid + 50];
        ws[(size_t)blockIdx.x * REC + tid] = acc;
    } else if (tid == 50) {
        float acc = 0.f;
        #pragma unroll
        for (int h = 0; h < 32; ++h) acc += s100[h][100];
        ws[(size_t)blockIdx.x * REC + 50] = acc;
    }
}

// ---- R8's proven float2 quad kernel: fallback for odd T ----
__global__ __launch_bounds__(512, 4) void attn_pass1_f2(
    const float* __restrict__ query, const float* __restrict__ ql_w,
    const float* __restrict__ qWp, float* __restrict__ ws,
    int T, int totalGroups)
{
    const float qW = qWp[0];
    const int tid = threadIdx.x;
    const int q   = tid & 3;
    const int g   = blockIdx.x * 128 + (tid >> 2);

    float2 w01[7];
    #pragma unroll
    for (int t = 0; t < 6; ++t) {
        const int s = q + 4 * t;
        w01[t] = *(const float2*)(ql_w + 2 * s);
    }
    w01[6] = (q == 0) ? *(const float2*)(ql_w + 48) : make_float2(0.f, 0.f);
    const int d6 = (q == 0) ? 192 : 160;

    float sw = 0.f, saw = 0.f;
    #pragma unroll
    for (int t = 0; t < 7; ++t) {
        sw  += w01[t].x + w01[t].y;
        saw += fabsf(w01[t].x) + fabsf(w01[t].y);
    }
    sw  = dpp_add(dpp_add(sw,  DPP_QXOR1), DPP_QXOR2);
    saw = dpp_add(dpp_add(saw, DPP_QXOR1), DPP_QXOR2);
    const float M0  = (saw > 80.f) ? (saw - 80.f) : 0.f;
    const float c2  = 2.f * qW * LOG2E;
    const float K   = (sw - M0) * LOG2E;
    const float n2l = -2.f * LOG2E;

    float2 z[7];
    #pragma unroll
    for (int t = 0; t < 7; ++t) z[t] = make_float2(0.f, 0.f);
    float se = 0.f;

    const int G = totalGroups;
    const char* rp = (const char*)(query + (size_t)g * NF) + (q << 3);
    const size_t step = (size_t)G * NF * sizeof(float);

    for (int row = g; row < T; row += G, rp += step) {
        float2 x0 = *(const float2*)(rp);
        float2 x1 = *(const float2*)(rp + 32);
        float2 x2 = *(const float2*)(rp + 64);
        float2 x3 = *(const float2*)(rp + 96);
        float2 x4 = *(const float2*)(rp + 128);
        float2 x5 = *(const float2*)(rp + 160);
        float2 x6 = *(const float2*)(rp + d6);

        float p = 0.f, r;
        r = RCPE(x0.x); p = fmaf(w01[0].x, r, p);
        r = RCPE(x0.y); p = fmaf(w01[0].y, r, p);
        r = RCPE(x1.x); p = fmaf(w01[1].x, r, p);
        r = RCPE(x1.y); p = fmaf(w01[1].y, r, p);
        r = RCPE(x2.x); p = fmaf(w01[2].x, r, p);
        r = RCPE(x2.y); p = fmaf(w01[2].y, r, p);
        r = RCPE(x3.x); p = fmaf(w01[3].x, r, p);
        r = RCPE(x3.y); p = fmaf(w01[3].y, r, p);
        r = RCPE(x4.x); p = fmaf(w01[4].x, r, p);
        r = RCPE(x4.y); p = fmaf(w01[4].y, r, p);
        r = RCPE(x5.x); p = fmaf(w01[5].x, r, p);
        r = RCPE(x5.y); p = fmaf(w01[5].y, r, p);
        r = RCPE(x6.x); p = fmaf(w01[6].x, r, p);
        r = RCPE(x6.y); p = fmaf(w01[6].y, r, p);

        p = dpp_add(dpp_add(p, DPP_QXOR1), DPP_QXOR2);
        const float e = __builtin_amdgcn_exp2f(fmaf(p, n2l, K));

        se += e;
        z[0].x = fmaf(e, x0.x, z[0].x); z[0].y = fmaf(e, x0.y, z[0].y);
        z[1].x = fmaf(e, x1.x, z[1].x); z[1].y = fmaf(e, x1.y, z[1].y);
        z[2].x = fmaf(e, x2.x, z[2].x); z[2].y = fmaf(e, x2.y, z[2].y);
        z[3].x = fmaf(e, x3.x, z[3].x); z[3].y = fmaf(e, x3.y, z[3].y);
        z[4].x = fmaf(e, x4.x, z[4].x); z[4].y = fmaf(e, x4.y, z[4].y);
        z[5].x = fmaf(e, x5.x, z[5].x); z[5].y = fmaf(e, x5.y, z[5].y);
        z[6].x = fmaf(e, x6.x, z[6].x); z[6].y = fmaf(e, x6.y, z[6].y);
    }

    #pragma unroll
    for (int t = 0; t < 7; ++t) {
        z[t].x = dpp_add(dpp_add(z[t].x, DPP_ROR4), DPP_ROR8);
        z[t].y = dpp_add(dpp_add(z[t].y, DPP_ROR4), DPP_ROR8);
    }
    se = dpp_add(dpp_add(se, DPP_ROR4), DPP_ROR8);

    __shared__ float sz[32][REC];
    if ((tid & 15) < 4) {
        const int eidx = tid >> 4;
        #pragma unroll
        for (int t = 0; t < 6; ++t) {
            const int s = q + 4 * t;
            *(float2*)&sz[eidx][2 * s] = z[t];
        }
        if (q == 0) {
            *(float2*)&sz[eidx][48] = z[6];
            sz[eidx][50] = se;
            sz[eidx][51] = 0.f;
        }
    }
    __syncthreads();

    if (tid < 51) {
        float acc = 0.f;
        #pragma unroll
        for (int h = 0; h < 32; ++h) acc += sz[h][tid];
        ws[(size_t)blockIdx.x * REC + tid] = acc;
    }
}

// Pass 2: plain sum of B records (50 z + s each), divide, store.
__global__ __launch_bounds__(1024) void attn_pass2(
    const float* __restrict__ ws, float* __restrict__ out, int B)
{
    __shared__ float zacc[16][REC];
    const int tid = threadIdx.x;
    const int w = tid >> 6, lane = tid & 63;

    if (lane < 51) {
        float acc = 0.f;
        int b = w;
        for (; b + 112 < B; b += 128) {
            acc += ws[(size_t)(b      ) * REC + lane]
                 + ws[(size_t)(b +  16) * REC + lane]
                 + ws[(size_t)(b +  32) * REC + lane]
                 + ws[(size_t)(b +  48) * REC + lane]
                 + ws[(size_t)(b +  64) * REC + lane]
                 + ws[(size_t)(b +  80) * REC + lane]
                 + ws[(size_t)(b +  96) * REC + lane]
                 + ws[(size_t)(b + 112) * REC + lane];
        }
        for (; b < B; b += 16)
            acc += ws[(size_t)b * REC + lane];
        zacc[w][lane] = acc;
    }
    __syncthreads();
    if (tid < NF) {
        float Z = 0.f, S = 0.f;
        #pragma unroll
        for (int h = 0; h < 16; ++h) { Z += zacc[h][tid]; S += zacc[h][50]; }
        out[tid] = Z / S;
    }
}

extern "C" void kernel_launch(void* const* d_in, const int* in_sizes, int n_in,
                              void* d_out, int out_size, void* d_ws, size_t ws_size,
                              hipStream_t stream) {
    const float* query = (const float*)d_in[0];
    const float* ql_w  = (const float*)d_in[1];
    const float* qW    = (const float*)d_in[2];
    float* out = (float*)d_out;
    float* ws  = (float*)d_ws;

    const int T = in_sizes[0] / NF;

    int B = NBLK;
    size_t need = (size_t)B * REC * sizeof(float);
    if (ws_size < need) {
        B = (int)(ws_size / (REC * sizeof(float)));
        if (B < 1) B = 1;
    }

    const int totalGroups = B * 128;
    if ((T & 1) == 0) {
        hipLaunchKernelGGL(attn_pass1_even, dim3(B), dim3(512), 0, stream,
                           query, ql_w, qW, ws, T, totalGroups);
    } else {
        hipLaunchKernelGGL(attn_pass1_f2, dim3(B), dim3(512), 0, stream,
                           query, ql_w, qW, ws, T, totalGroups);
    }
    hipLaunchKernelGGL(attn_pass2, dim3(1), dim3(1024), 0, stream,
                       ws, out, B);
}